// Round 1
// baseline (477.355 us; speedup 1.0000x reference)
//
#include <hip/hip_runtime.h>
#include <stdint.h>

// Problem constants (B=4, L=2048, D=2048)
#define B_DIM 4
#define L_DIM 2048
#define D_DIM 2048
#define M_DIM 8192              // B*L token rows
#define K_DIM 2048
#define N_DIM 2048
#define WELEM (D_DIM * D_DIM)   // 4194304 elements per weight
#define CHUNK 32
#define NCH (L_DIM / CHUNK)     // 64 chunks per sequence

typedef int v4i __attribute__((ext_vector_type(4)));
typedef unsigned short bfraw;   // bf16 bit pattern

#define AS1 __attribute__((address_space(1)))
#define AS3 __attribute__((address_space(3)))

__device__ __forceinline__ void gl_lds16(const void* g, void* l) {
    // async global->LDS, 16B per lane; LDS dst = wave-uniform base + lane*16
    __builtin_amdgcn_global_load_lds((AS1 void*)g, (AS3 void*)l, 16, 0, 0);
}

// raw workgroup barrier WITHOUT implicit vmcnt(0) drain (unlike __syncthreads);
// "memory" clobbers stop the compiler moving LDS/global ops across it.
__device__ __forceinline__ void wg_barrier() {
    asm volatile("" ::: "memory");
    __builtin_amdgcn_s_barrier();
    asm volatile("" ::: "memory");
}

__device__ __forceinline__ float sigmoidf_(float x) { return 1.0f / (1.0f + expf(-x)); }

__device__ __forceinline__ float bf2f(bfraw u) {
    union { unsigned int i; float f; } c; c.i = ((unsigned int)u) << 16; return c.f;
}
__device__ __forceinline__ bfraw f2bf(float f) {
    union { float f; unsigned int i; } c; c.f = f;
    unsigned int lsb = (c.i >> 16) & 1;
    c.i += 0x7fffu + lsb;                   // round-to-nearest-even
    return (bfraw)(c.i >> 16);
}

__device__ __forceinline__ void store_out(float* p, float v) { *p = v; }
__device__ __forceinline__ void store_out(bfraw* p, float v) { *p = f2bf(v); }

// ---------------- block reductions (256 threads = 4 waves) ----------------
__device__ __forceinline__ float block_sum256(float v) {
#pragma unroll
    for (int off = 32; off > 0; off >>= 1) v += __shfl_down(v, off);
    __shared__ float sb[4];
    int lane = threadIdx.x & 63, wv = threadIdx.x >> 6;
    __syncthreads();
    if (lane == 0) sb[wv] = v;
    __syncthreads();
    return sb[0] + sb[1] + sb[2] + sb[3];
}

__device__ __forceinline__ void block_sum_max256(float& s, float& m) {
#pragma unroll
    for (int off = 32; off > 0; off >>= 1) {
        s += __shfl_down(s, off);
        m = fmaxf(m, __shfl_down(m, off));
    }
    __shared__ float sb2[8];
    int lane = threadIdx.x & 63, wv = threadIdx.x >> 6;
    __syncthreads();
    if (lane == 0) { sb2[wv] = s; sb2[4 + wv] = m; }
    __syncthreads();
    s = sb2[0] + sb2[1] + sb2[2] + sb2[3];
    m = fmaxf(fmaxf(sb2[4], sb2[5]), fmaxf(sb2[6], sb2[7]));
}

// ---------------- weight stats: mean|W| per weight ----------------
__global__ void wstats1(const float* __restrict__ w0, const float* __restrict__ w1,
                        const float* __restrict__ w2, const float* __restrict__ w3,
                        float* __restrict__ wpart) {
    int w = blockIdx.x >> 7;
    int slice = blockIdx.x & 127;
    const float* W = (w == 0) ? w0 : ((w == 1) ? w1 : ((w == 2) ? w2 : w3));
    const float4* p = (const float4*)(W + (size_t)slice * (WELEM / 128));
    float s = 0.f;
    for (int i = threadIdx.x; i < (WELEM / 128 / 4); i += 256) {
        float4 v = p[i];
        s += fabsf(v.x) + fabsf(v.y) + fabsf(v.z) + fabsf(v.w);
    }
    s = block_sum256(s);
    if (threadIdx.x == 0) wpart[blockIdx.x] = s;
}

__global__ void wstats2(const float* __restrict__ wpart, float* __restrict__ wdeq) {
    int w = threadIdx.x >> 6;
    int lane = threadIdx.x & 63;
    float s = wpart[w * 128 + lane] + wpart[w * 128 + 64 + lane];
#pragma unroll
    for (int off = 32; off > 0; off >>= 1) s += __shfl_down(s, off);
    if (lane == 0) wdeq[w] = fmaxf(s * (1.0f / (float)WELEM), 1e-5f);
}

// ---------------- merged: weight ternary quant (blocks 0..16383) + act quant ------
__global__ void quant_all(const float* __restrict__ w0, const float* __restrict__ w1,
                          const float* __restrict__ w2, const float* __restrict__ w3,
                          const float* __restrict__ wdeq, int8_t* __restrict__ wq,
                          const float* __restrict__ x, int8_t* __restrict__ xq,
                          float* __restrict__ adeq) {
    if (blockIdx.x < 16384) {
        // ----- weight ternary quantization: one float4 group per thread -----
        size_t idx = (size_t)blockIdx.x * 256 + threadIdx.x;
        int w = (int)(idx >> 20);                               // WELEM/4 = 2^20 groups/weight
        size_t g = idx & ((1u << 20) - 1);
        const float* W = (w == 0) ? w0 : ((w == 1) ? w1 : ((w == 2) ? w2 : w3));
        float inv = 1.0f / wdeq[w];                             // = ws
        float4 v = ((const float4*)W)[g];
        int q0 = (int)rintf(v.x * inv); q0 = q0 < -1 ? -1 : (q0 > 1 ? 1 : q0);
        int q1 = (int)rintf(v.y * inv); q1 = q1 < -1 ? -1 : (q1 > 1 ? 1 : q1);
        int q2 = (int)rintf(v.z * inv); q2 = q2 < -1 ? -1 : (q2 > 1 ? 1 : q2);
        int q3 = (int)rintf(v.w * inv); q3 = q3 < -1 ? -1 : (q3 > 1 ? 1 : q3);
        uint32_t p = (uint32_t)(q0 & 0xff) | ((uint32_t)(q1 & 0xff) << 8) |
                     ((uint32_t)(q2 & 0xff) << 16) | ((uint32_t)(q3 & 0xff) << 24);
        ((uint32_t*)(wq + (size_t)w * WELEM))[g] = p;
        return;
    }
    // ----- activation rmsnorm + int8 quant (one row per block) -----
    int row = blockIdx.x - 16384, tid = threadIdx.x;
    const float4* xr = (const float4*)(x + (size_t)row * D_DIM);
    float4 a = xr[2 * tid], b = xr[2 * tid + 1];
    float v[8] = {a.x, a.y, a.z, a.w, b.x, b.y, b.z, b.w};
    float ss = 0.f, mx = 0.f;
#pragma unroll
    for (int j = 0; j < 8; j++) { ss += v[j] * v[j]; mx = fmaxf(mx, fabsf(v[j])); }
    block_sum_max256(ss, mx);
    float inv = rsqrtf(ss * (1.0f / (float)D_DIM) + 1e-5f);
    float anc = fmaxf(mx * inv, 1e-5f);      // max|xn| clipped
    float s = 127.0f / anc;
    if (tid == 0) adeq[row] = anc * (1.0f / 127.0f);
    float sc = inv * s;
    int q[8];
#pragma unroll
    for (int j = 0; j < 8; j++) {
        int t = (int)rintf(v[j] * sc);
        q[j] = t < -128 ? -128 : (t > 127 ? 127 : t);
    }
    uint32_t lo = (uint32_t)(q[0] & 0xff) | ((uint32_t)(q[1] & 0xff) << 8) |
                  ((uint32_t)(q[2] & 0xff) << 16) | ((uint32_t)(q[3] & 0xff) << 24);
    uint32_t hi = (uint32_t)(q[4] & 0xff) | ((uint32_t)(q[5] & 0xff) << 8) |
                  ((uint32_t)(q[6] & 0xff) << 16) | ((uint32_t)(q[7] & 0xff) << 24);
    ((uint2*)(xq + (size_t)row * D_DIM))[tid] = make_uint2(lo, hi);
}

// ---------------- int8 x ternary GEMM core: 128x256 tile, BK=64B, 4 waves ---------
// Wave wv: wm=(wv&1)*64, wn=(wv>>1)*128 -> 64x128 per wave, 4 afrag + 8 bfrag,
// 32 mfma_i32_16x16x64_i8 per K-iter.
//
// LDS layout (fragment-order): each 16-row group is a 1KB block where lane l's
// MFMA fragment (row=l&15, kbytes (l>>4)*16..) sits at byte l*16.  Achieved by
// pre-permuting the per-lane GLOBAL source address (global_load_lds writes
// LDS linearly at base+lane*16).  ds_read_b128 is then a linear 1KB wave read:
// zero bank conflicts, no per-fragment address math.
//
// Pipeline: double-buffered LDS, counted vmcnt(6) (tile t+1's 6 loads stay in
// flight across both barriers — never drain to 0 in the main loop), raw
// s_barrier (no implicit vmcnt(0)), setprio(1) around the MFMA cluster.
#define BM 128
#define BN 256
#define BKB 64

template <typename OutT>
__device__ __forceinline__ void gemm_core(
    const int8_t* __restrict__ A, const int8_t* __restrict__ Bw,
    const float* __restrict__ adeq, float wsc,
    int m0, int n0, OutT* __restrict__ Cout) {
    __shared__ int8_t sA[2][BM * BKB];   // 2 x 8 KB
    __shared__ int8_t sB[2][BN * BKB];   // 2 x 16 KB
    int lane = threadIdx.x & 63;
    int wv = threadIdx.x >> 6;
    int wm = (wv & 1) * 64;
    int wn = (wv >> 1) * 128;
    int qq = lane >> 4;             // k-chunk (16B) within 64B row slice
    int mr = lane & 15;             // row within 16-row group

    const v4i vzero = {0, 0, 0, 0};
    v4i acc[4][8];
#pragma unroll
    for (int i = 0; i < 4; i++)
#pragma unroll
        for (int j = 0; j < 8; j++) acc[i][j] = vzero;

    // per-lane pre-permuted global source base: row = mr, k-chunk = qq
    const int8_t* Asrc = A + (size_t)(m0 + mr) * K_DIM + qq * 16;
    const int8_t* Bsrc = Bw + (size_t)(n0 + mr) * K_DIM + qq * 16;
    const int agrp = (wv & 1) * 4;   // this wave's first A group (16-row blocks)
    const int bgrp = (wv >> 1) * 8;  // this wave's first B group

    // per wave: 2 A groups (wv, 4+wv) + 4 B groups (wv, 4+wv, 8+wv, 12+wv)
#define STAGE(c, kt) do {                                                         \
    gl_lds16(Asrc + (size_t)(wv * 16) * K_DIM + (kt),        &sA[c][wv * 1024]);        \
    gl_lds16(Asrc + (size_t)(64 + wv * 16) * K_DIM + (kt),   &sA[c][(4 + wv) * 1024]);  \
    gl_lds16(Bsrc + (size_t)(wv * 16) * K_DIM + (kt),        &sB[c][wv * 1024]);        \
    gl_lds16(Bsrc + (size_t)(64 + wv * 16) * K_DIM + (kt),   &sB[c][(4 + wv) * 1024]);  \
    gl_lds16(Bsrc + (size_t)(128 + wv * 16) * K_DIM + (kt),  &sB[c][(8 + wv) * 1024]);  \
    gl_lds16(Bsrc + (size_t)(192 + wv * 16) * K_DIM + (kt),  &sB[c][(12 + wv) * 1024]); \
  } while (0)

    STAGE(0, 0);
    int cur = 0;
#pragma unroll 2
    for (int kt = 0; kt < K_DIM; kt += BKB) {
        if (kt + BKB < K_DIM) {
            STAGE(cur ^ 1, kt + BKB);                       // prefetch tile t+1
            asm volatile("s_waitcnt vmcnt(6)" ::: "memory");// my tile-t loads done
        } else {
            asm volatile("s_waitcnt vmcnt(0)" ::: "memory");
        }
        wg_barrier();        // all waves' tile-t loads landed in sX[cur]

        v4i afrag[4], bfrag[8];
#pragma unroll
        for (int i = 0; i < 4; i++)
            afrag[i] = *(const v4i*)(&sA[cur][(agrp + i) * 1024 + lane * 16]);
#pragma unroll
        for (int j = 0; j < 8; j++)
            bfrag[j] = *(const v4i*)(&sB[cur][(bgrp + j) * 1024 + lane * 16]);

        __builtin_amdgcn_s_setprio(1);
#pragma unroll
        for (int i = 0; i < 4; i++)
#pragma unroll
            for (int j = 0; j < 8; j++)
                acc[i][j] = __builtin_amdgcn_mfma_i32_16x16x64_i8(afrag[i], bfrag[j], acc[i][j], 0, 0, 0);
        __builtin_amdgcn_s_setprio(0);

        wg_barrier();        // all waves done reading sX[cur]; safe to overwrite
        cur ^= 1;
    }
#undef STAGE

    int cc = mr;
#pragma unroll
    for (int i = 0; i < 4; i++) {
#pragma unroll
        for (int r = 0; r < 4; r++) {
            int row = m0 + wm + i * 16 + qq * 4 + r;   // C/D: row = quad*4 + reg
            float rs = adeq[row] * wsc;
            OutT* crow = Cout + (size_t)row * N_DIM + n0 + wn + cc;
#pragma unroll
            for (int j = 0; j < 8; j++) store_out(crow + j * 16, (float)acc[i][j][r] * rs);
        }
    }
}

// merged i/f/g GEMM: grid.x = 24 (8 N-tiles x 3 weights), grid.y = 64 M-tiles
__global__ __launch_bounds__(256, 2) void gemm_ifg(
    const int8_t* __restrict__ xq, const int8_t* __restrict__ wq,
    const float* __restrict__ adeq, const float* __restrict__ wdeq,
    bfraw* __restrict__ bufI, bfraw* __restrict__ bufF, bfraw* __restrict__ bufG) {
    int widx = blockIdx.x >> 3;
    int n0 = (blockIdx.x & 7) * BN;
    int m0 = blockIdx.y * BM;
    bfraw* outp = (widx == 0) ? bufI : ((widx == 1) ? bufF : bufG);
    gemm_core<bfraw>(xq, wq + (size_t)widx * WELEM, adeq, wdeq[widx], m0, n0, outp);
}

// final o GEMM: fp32 out. grid.x = 8, grid.y = 64
__global__ __launch_bounds__(256, 2) void gemm_o(
    const int8_t* __restrict__ oq, const int8_t* __restrict__ wq,
    const float* __restrict__ odeq, const float* __restrict__ wdeq,
    float* __restrict__ out) {
    gemm_core<float>(oq, wq + 3 * (size_t)WELEM, odeq, wdeq[3], blockIdx.y * BM,
                     blockIdx.x * BN, out);
}

// ---------------- chunked scan with fused activations ----------------
// f_t = sigmoid(fL_t); i_t = silu(iL_t)*(1-f_t); h_t = f_t*h_{t-1} + i_t
__global__ void scan1(const bfraw* __restrict__ iL, const bfraw* __restrict__ fL,
                      float* __restrict__ Fc, float* __restrict__ Ic) {
    int idx = blockIdx.x * 256 + threadIdx.x;   // 4*64*2048
    int d = idx & (D_DIM - 1);
    int c = (idx >> 11) & (NCH - 1);
    int b = idx >> 17;
    size_t base = ((size_t)(b * L_DIM + c * CHUNK)) * D_DIM + d;
    float F = 1.f, h = 0.f;
#pragma unroll 4
    for (int t = 0; t < CHUNK; t++) {
        float fr = bf2f(fL[base + (size_t)t * D_DIM]);
        float ir = bf2f(iL[base + (size_t)t * D_DIM]);
        float fv = sigmoidf_(fr);
        float iv = ir * sigmoidf_(ir) * (1.0f - fv);
        h = fv * h + iv;
        F *= fv;
    }
    size_t ci = ((size_t)b * NCH + c) * D_DIM + d;
    Fc[ci] = F;
    Ic[ci] = h;
}

__global__ void scan2(const float* __restrict__ Fc, const float* __restrict__ Ic,
                      float* __restrict__ Hc) {
    int idx = blockIdx.x * 256 + threadIdx.x;   // 8192
    int d = idx & (D_DIM - 1);
    int b = idx >> 11;
    float h = 0.f;
    for (int c0 = 0; c0 < NCH; c0 += 8) {
        float F[8], I[8];
#pragma unroll
        for (int j = 0; j < 8; j++) {
            size_t ci = ((size_t)b * NCH + c0 + j) * D_DIM + d;
            F[j] = Fc[ci];
            I[j] = Ic[ci];
        }
#pragma unroll
        for (int j = 0; j < 8; j++) {
            size_t ci = ((size_t)b * NCH + c0 + j) * D_DIM + d;
            Hc[ci] = h;
            h = F[j] * h + I[j];
        }
    }
}

__global__ void scan3(const bfraw* __restrict__ iL, const bfraw* __restrict__ fL,
                      const float* __restrict__ Hc, bfraw* __restrict__ hout) {
    int idx = blockIdx.x * 256 + threadIdx.x;
    int d = idx & (D_DIM - 1);
    int c = (idx >> 11) & (NCH - 1);
    int b = idx >> 17;
    size_t base = ((size_t)(b * L_DIM + c * CHUNK)) * D_DIM + d;
    float h = Hc[((size_t)b * NCH + c) * D_DIM + d];
#pragma unroll 4
    for (int t = 0; t < CHUNK; t++) {
        size_t a = base + (size_t)t * D_DIM;
        float fr = bf2f(fL[a]);
        float ir = bf2f(iL[a]);
        float fv = sigmoidf_(fr);
        float iv = ir * sigmoidf_(ir) * (1.0f - fv);
        h = fv * h + iv;
        hout[a] = f2bf(h);
    }
}

// ---------------- g-path: o = rmsnorm(g)*gw * h*sigmoid(h); rmsnorm+quant o ---------
union BF8 { uint4 u; bfraw s[8]; };

__global__ void gout_quant(const bfraw* __restrict__ gL, const bfraw* __restrict__ h,
                           const float* __restrict__ gw, int8_t* __restrict__ oq,
                           float* __restrict__ odeq) {
    int row = blockIdx.x, tid = threadIdx.x;
    BF8 g8, h8;
    g8.u = ((const uint4*)(gL + (size_t)row * D_DIM))[tid];
    float gv[8];
    float ss = 0.f;
#pragma unroll
    for (int j = 0; j < 8; j++) { gv[j] = bf2f(g8.s[j]); ss += gv[j] * gv[j]; }
    float ssg = block_sum256(ss);
    float invg = rsqrtf(ssg * (1.0f / (float)D_DIM) + 1e-5f);

    h8.u = ((const uint4*)(h + (size_t)row * D_DIM))[tid];
    const float4* wr = (const float4*)gw;
    float4 w0 = wr[2 * tid], w1 = wr[2 * tid + 1];
    float wv[8] = {w0.x, w0.y, w0.z, w0.w, w1.x, w1.y, w1.z, w1.w};
    float o[8];
    float sso = 0.f, amax = 0.f;
#pragma unroll
    for (int j = 0; j < 8; j++) {
        float hv = bf2f(h8.s[j]);
        o[j] = gv[j] * invg * wv[j] * hv * sigmoidf_(hv);
        sso += o[j] * o[j];
        amax = fmaxf(amax, fabsf(o[j]));
    }
    block_sum_max256(sso, amax);
    float invo = rsqrtf(sso * (1.0f / (float)D_DIM) + 1e-5f);
    float anc = fmaxf(amax * invo, 1e-5f);
    float s = 127.0f / anc;
    if (tid == 0) odeq[row] = anc * (1.0f / 127.0f);
    float sc = invo * s;
    int q[8];
#pragma unroll
    for (int j = 0; j < 8; j++) {
        int t = (int)rintf(o[j] * sc);
        q[j] = t < -128 ? -128 : (t > 127 ? 127 : t);
    }
    uint32_t lo = (uint32_t)(q[0] & 0xff) | ((uint32_t)(q[1] & 0xff) << 8) |
                  ((uint32_t)(q[2] & 0xff) << 16) | ((uint32_t)(q[3] & 0xff) << 24);
    uint32_t hi = (uint32_t)(q[4] & 0xff) | ((uint32_t)(q[5] & 0xff) << 8) |
                  ((uint32_t)(q[6] & 0xff) << 16) | ((uint32_t)(q[7] & 0xff) << 24);
    ((uint2*)(oq + (size_t)row * D_DIM))[tid] = make_uint2(lo, hi);
}

// ---------------- driver ----------------
extern "C" void kernel_launch(void* const* d_in, const int* in_sizes, int n_in,
                              void* d_out, int out_size, void* d_ws, size_t ws_size,
                              hipStream_t stream) {
    const float* x  = (const float*)d_in[0];
    const float* Wi = (const float*)d_in[1];
    const float* Wf = (const float*)d_in[2];
    const float* Wg = (const float*)d_in[3];
    const float* Wo = (const float*)d_in[4];
    const float* gw = (const float*)d_in[5];
    float* out = (float*)d_out;

    char* ws = (char*)d_ws;
    float*  wdeq  = (float*)(ws + 0);                 // 4 floats
    float*  wpart = (float*)(ws + 256);               // 512 partials
    float*  adeq  = (float*)(ws + 0x10000);           // 8192 per-row act dequant
    float*  odeq  = (float*)(ws + 0x20000);           // 8192 per-row o dequant
    int8_t* xq    = (int8_t*)(ws + 0x100000);         // 16MB int8 x; reused as oq
    int8_t* wq    = (int8_t*)(ws + 0x1100000);        // 4 x 4MB ternary weights
    float*  Fc    = (float*)(ws + 0x2100000);         // 2MB chunk f-products
    float*  Ic    = (float*)(ws + 0x2300000);         // 2MB chunk partial h
    float*  Hc    = (float*)(ws + 0x2500000);         // 2MB chunk carries
    bfraw*  bufI  = (bfraw*)(ws + 0x4000000);         // 32MB bf16: i_lin
    bfraw*  bufF  = (bfraw*)(ws + 0x6000000);         // 32MB bf16: f_lin
    bfraw*  bufG  = (bfraw*)(ws + 0x8000000);         // 32MB bf16: g_lin
    bfraw*  hbuf  = (bfraw*)(ws + 0xA000000);         // 32MB bf16: h

    wstats1<<<512, 256, 0, stream>>>(Wi, Wf, Wg, Wo, wpart);
    wstats2<<<1, 256, 0, stream>>>(wpart, wdeq);
    quant_all<<<16384 + 8192, 256, 0, stream>>>(Wi, Wf, Wg, Wo, wdeq, wq, x, xq, adeq);

    gemm_ifg<<<dim3(24, M_DIM / BM), 256, 0, stream>>>(xq, wq, adeq, wdeq, bufI, bufF, bufG);

    scan1<<<2048, 256, 0, stream>>>(bufI, bufF, Fc, Ic);
    scan2<<<32, 256, 0, stream>>>(Fc, Ic, Hc);
    scan3<<<2048, 256, 0, stream>>>(bufI, bufF, Hc, hbuf);

    gout_quant<<<M_DIM, 256, 0, stream>>>(bufG, hbuf, gw, xq /*as oq*/, odeq);
    gemm_o<<<dim3(N_DIM / BN, M_DIM / BM), 256, 0, stream>>>(xq /*oq*/, wq, odeq, wdeq, out);

    (void)in_sizes; (void)n_in; (void)out_size; (void)ws_size;
}